// Round 6
// baseline (379.630 us; speedup 1.0000x reference)
//
#include <hip/hip_runtime.h>

// ---------------------------------------------------------------------------
// SelfCrossAttention: B=4, T=1024+1024, d=512, H=8, hd=64. fp32 I/O,
// bf16 MFMA internals.
// prep (X->bf16; W_self/W_cross -> wt[n][k] bf16, q pre-scaled 1/8;
//       W_proj -> wtp[n][k] bf16)
//   -> qkv (LDS-free 128x128 GEMM, direct-global b128 fragments;
//           V written transposed [bh][j][t])
//   -> attn (S^T flash: P exits QK^T in 16x16x16 B-operand layout, l via
//            all-ones-A MFMA, v_perm packing; 4-way key split, LDS merge)
//   -> proj (LDS-free, fp32 out, tuple split).
// ---------------------------------------------------------------------------

typedef short     bf16x8 __attribute__((ext_vector_type(8)));
typedef short     bf16x4 __attribute__((ext_vector_type(4)));
typedef float     f32x4  __attribute__((ext_vector_type(4)));
typedef int       i32x4  __attribute__((ext_vector_type(4)));

#define DI __device__ __forceinline__

DI unsigned short f2b(float f) {            // fp32 -> bf16 bits, RNE-ish
    union { float f; unsigned int u; } x; x.f = f;
    unsigned int r = x.u + 0x7fffu + ((x.u >> 16) & 1u);
    return (unsigned short)(r >> 16);
}
DI unsigned int fbits(float f) { union { float f; unsigned int u; } x; x.f = f; return x.u; }
DI float bitsf(unsigned int u) { union { unsigned int u; float f; } x; x.u = u; return x.f; }
DI float b2f(unsigned short v) { return bitsf(((unsigned int)v) << 16); }

// ---------------------------------------------------------------------------
// prep: [0,2048): X fp32 -> bf16 flat.
//       [2048,2432): W_self/W_cross -> wt[src][n][k], q-section (n<512) *0.125
//       [2432,2496): W_proj -> wtp[n][k]
// ---------------------------------------------------------------------------
__global__ __launch_bounds__(256)
void prep_kernel(const float* __restrict__ Xs, const float* __restrict__ Xc,
                 const float* __restrict__ Ws, const float* __restrict__ Wc,
                 const float* __restrict__ Wp,
                 unsigned short* __restrict__ xb, unsigned short* __restrict__ wt,
                 unsigned short* __restrict__ wtp)
{
    const int bid = blockIdx.x, tid = threadIdx.x;
    if (bid < 2048) {
        int idx = bid * 2048 + tid * 8;
        const float* s = (idx < 2097152) ? (Xs + idx) : (Xc + idx - 2097152);
        f32x4 a0 = *(const f32x4*)s;
        f32x4 a1 = *(const f32x4*)(s + 4);
        bf16x8 v;
#pragma unroll
        for (int j = 0; j < 4; ++j) {
            ((unsigned short*)&v)[j]     = f2b(a0[j]);
            ((unsigned short*)&v)[4 + j] = f2b(a1[j]);
        }
        *(bf16x8*)(xb + idx) = v;
        return;
    }
    __shared__ unsigned short Tt[64 * 72];
    const float* W;
    unsigned short* dst;
    int k0, n0, ldn;
    float sc = 1.0f;
    if (bid < 2432) {
        int tj  = bid - 2048;
        int src = tj >= 192;  tj -= src * 192;
        k0  = (tj / 24) * 64;
        n0  = (tj % 24) * 64;
        W   = src ? Wc : Ws;
        ldn = 1536;
        dst = wt + (size_t)src * 786432;
        if (n0 < 512) sc = 0.125f;
    } else {
        int tj = bid - 2432;
        k0  = (tj >> 3) * 64;
        n0  = (tj & 7) * 64;
        W   = Wp;
        ldn = 512;
        dst = wtp;
    }
#pragma unroll
    for (int r = 0; r < 4; ++r) {
        int g  = tid + r * 256;
        int kr = g >> 4, nc4 = (g & 15) * 4;
        f32x4 v = *(const f32x4*)(W + (size_t)(k0 + kr) * ldn + n0 + nc4);
#pragma unroll
        for (int u = 0; u < 4; ++u)
            Tt[(nc4 + u) * 72 + kr] = f2b(v[u] * sc);
    }
    __syncthreads();
#pragma unroll
    for (int r = 0; r < 2; ++r) {
        int c = tid + r * 256;
        int nl = c >> 3, k8 = (c & 7) * 8;
        *(bf16x8*)(dst + (size_t)(n0 + nl) * 512 + k0 + k8) =
            *(const bf16x8*)(Tt + nl * 72 + k8);
    }
}

// ---------------------------------------------------------------------------
// QKV: xb @ wt^T + bias, LDS-free: A- and B-fragments are direct b128 global
// loads (both row-major k-contiguous), L2-served reuse, no barriers.
// 128x128 per block (4 waves x 64x64). q/k -> [bh][t][j]; v -> vt[bh][j][t].
// ---------------------------------------------------------------------------
__global__ __launch_bounds__(256)
void qkv_kernel(const unsigned short* __restrict__ xb,
                const unsigned short* __restrict__ wt,
                const float* __restrict__ bs, const float* __restrict__ bc,
                unsigned short* __restrict__ qb, unsigned short* __restrict__ kb,
                unsigned short* __restrict__ vtb)
{
    const int src = blockIdx.z;
    const int m0 = blockIdx.x * 128, n0 = blockIdx.y * 128;
    const float* bias = src ? bc : bs;
    const unsigned short* X = xb + (size_t)src * 2097152;
    const unsigned short* W = wt + (size_t)src * 786432;

    const int tid = threadIdx.x, lane = tid & 63, w = tid >> 6;
    const int quad = lane >> 4, r16 = lane & 15;
    const int mrow = (w >> 1) * 64, ncol = (w & 1) * 64;

    const f32x4 fz = {0.f, 0.f, 0.f, 0.f};
    f32x4 acc[4][4];
#pragma unroll
    for (int a = 0; a < 4; ++a)
#pragma unroll
        for (int b = 0; b < 4; ++b) acc[a][b] = fz;

    const unsigned short* Ab = X + (size_t)(m0 + mrow + r16) * 512 + quad * 8;
    const unsigned short* Bb = W + (size_t)(n0 + ncol + r16) * 512 + quad * 8;

    for (int k0 = 0; k0 < 512; k0 += 32) {
        bf16x8 af[4], bfr[4];
#pragma unroll
        for (int ms = 0; ms < 4; ++ms)
            af[ms] = *(const bf16x8*)(Ab + (size_t)ms * 16 * 512 + k0);
#pragma unroll
        for (int ns = 0; ns < 4; ++ns)
            bfr[ns] = *(const bf16x8*)(Bb + (size_t)ns * 16 * 512 + k0);
#pragma unroll
        for (int ms = 0; ms < 4; ++ms)
#pragma unroll
            for (int ns = 0; ns < 4; ++ns)
                acc[ms][ns] = __builtin_amdgcn_mfma_f32_16x16x32_bf16(
                    af[ms], bfr[ns], acc[ms][ns], 0, 0, 0);
    }

#pragma unroll
    for (int ms = 0; ms < 4; ++ms)
#pragma unroll
        for (int ns = 0; ns < 4; ++ns) {
            int n = n0 + ncol + ns * 16 + r16;
            int sec = n >> 9, col = n & 511;
            int hh = col >> 6, j = col & 63;
            float bb = bias[n] * ((sec == 0) ? 0.125f : 1.0f);
            int mb = m0 + mrow + ms * 16 + quad * 4;
            int bi = mb >> 10, tg0 = (mb & 1023) + (src << 10);
            if (sec == 2) {                 // V: transposed packed store
                bf16x4 pk;
#pragma unroll
                for (int i = 0; i < 4; ++i)
                    pk[i] = (short)f2b(acc[ms][ns][i] + bb);
                *(bf16x4*)(vtb + (((size_t)(bi * 8 + hh) * 64 + j) << 11) + tg0) = pk;
            } else {
                unsigned short* dst = (sec == 0) ? qb : kb;
#pragma unroll
                for (int i = 0; i < 4; ++i)
                    dst[(((size_t)(bi * 8 + hh) * 2048 + tg0 + i) << 6) + j] =
                        f2b(acc[ms][ns][i] + bb);
            }
        }
}

// ---------------------------------------------------------------------------
// attn: S^T flash. Block 256 thr = 4 waves; block = 32 queries of one bh;
// each wave covers all 32 q x 8 K-tiles (4-way key split). l computed by
// all-ones-A MFMA from the SAME packed P regs (exactly consistent). Partials
// merged via LDS. Grid swizzled: each XCD sees 4 bh (L2-resident K/V).
// ---------------------------------------------------------------------------
__global__ __launch_bounds__(256)
void attn_kernel(const unsigned short* __restrict__ qb,
                 const unsigned short* __restrict__ kb,
                 const unsigned short* __restrict__ vt,
                 const int* __restrict__ t_self, const int* __restrict__ t_cross,
                 unsigned short* __restrict__ y)
{
    const int bid = blockIdx.x;
    const int bh = ((bid & 7) << 2) | ((bid >> 3) & 3);   // XCD-local bh group
    const int qt = bid >> 5;                              // 0..63 (32-q tiles)
    const int b = bh >> 3, h = bh & 7;
    const int tid = threadIdx.x, ksplit = tid >> 6, lane = tid & 63;
    const int quad = lane >> 4, r16 = lane & 15;

    const unsigned short* Q = qb + (size_t)bh * 131072;
    const unsigned short* K = kb + (size_t)bh * 131072;
    const unsigned short* V = vt + (size_t)bh * 131072;
    const int* tsb = t_self + b * 1024;
    const int* tcb = t_cross + b * 1024;

    __shared__ unsigned short Op[4][32 * 68];   // bf16 partial O^T per split
    __shared__ float Ls[4][32];

    const int q0 = qt * 32;

    bf16x8 qf[2][2];
#pragma unroll
    for (int g = 0; g < 2; ++g)
#pragma unroll
        for (int ks = 0; ks < 2; ++ks)
            qf[g][ks] = *(const bf16x8*)(Q + (size_t)(q0 + g * 16 + r16) * 64
                                           + ks * 32 + quad * 8);

    const int* tqp = (qt < 32) ? (tsb + qt * 32) : (tcb + (qt - 32) * 32);
    int tq[2];
#pragma unroll
    for (int g = 0; g < 2; ++g) tq[g] = tqp[g * 16 + r16];

    const f32x4 fz = {0.f, 0.f, 0.f, 0.f};
    f32x4 ot[2][4], al[2];
#pragma unroll
    for (int g = 0; g < 2; ++g) {
        al[g] = fz;
#pragma unroll
        for (int nt = 0; nt < 4; ++nt) ot[g][nt] = fz;
    }
    const bf16x4 ones = {(short)0x3F80, (short)0x3F80, (short)0x3F80, (short)0x3F80};

    for (int it = 0; it < 8; ++it) {
        const int kt = ksplit * 8 + it;
        const int krow = kt * 64;
        const int* tkp = (kt < 16) ? (tsb + krow) : (tcb + krow - 1024);

#pragma unroll
        for (int ct = 0; ct < 4; ++ct) {
            i32x4 tk = *(const i32x4*)(tkp + ct * 16 + quad * 4);
            const unsigned short* kr = K + (size_t)(krow + ct * 16 + r16) * 64;
            bf16x8 ka0 = *(const bf16x8*)(kr + quad * 8);
            bf16x8 ka1 = *(const bf16x8*)(kr + 32 + quad * 8);

            bf16x4 pf[2];
#pragma unroll
            for (int g = 0; g < 2; ++g) {
                f32x4 st = fz;
                st = __builtin_amdgcn_mfma_f32_16x16x32_bf16(ka0, qf[g][0], st, 0, 0, 0);
                st = __builtin_amdgcn_mfma_f32_16x16x32_bf16(ka1, qf[g][1], st, 0, 0, 0);
                float e[4];
#pragma unroll
                for (int i = 0; i < 4; ++i) {
                    float a = (tq[g] >= tk[i]) ? st[i] : -1e9f;  // select ARG, no inf
                    e[i] = __expf(fminf(a, 80.f));
                }
                union { unsigned int u[2]; bf16x4 v; } pu;     // truncate-pack
                pu.u[0] = __builtin_amdgcn_perm(fbits(e[1]), fbits(e[0]), 0x07060302u);
                pu.u[1] = __builtin_amdgcn_perm(fbits(e[3]), fbits(e[2]), 0x07060302u);
                pf[g] = pu.v;
                // l partial from the SAME stored-precision P (ones-A MFMA)
                al[g] = __builtin_amdgcn_mfma_f32_16x16x16bf16_1k(ones, pf[g], al[g], 0, 0, 0);
            }

            // O^T += V^T · P^T  (V^T A-frags direct b64 from global)
#pragma unroll
            for (int nt = 0; nt < 4; ++nt) {
                bf16x4 va = *(const bf16x4*)(V + (size_t)(nt * 16 + r16) * 2048
                                               + krow + ct * 16 + quad * 4);
                ot[0][nt] = __builtin_amdgcn_mfma_f32_16x16x16bf16_1k(va, pf[0], ot[0][nt], 0, 0, 0);
                ot[1][nt] = __builtin_amdgcn_mfma_f32_16x16x16bf16_1k(va, pf[1], ot[1][nt], 0, 0, 0);
            }
        }
    }

    // write partials (bf16 O^T, fp32 l) and merge
    unsigned short* opw = Op[ksplit];
#pragma unroll
    for (int g = 0; g < 2; ++g)
#pragma unroll
        for (int nt = 0; nt < 4; ++nt) {
            union { unsigned int u[2]; bf16x4 v; } pk;
            pk.u[0] = (unsigned int)f2b(ot[g][nt][0]) | ((unsigned int)f2b(ot[g][nt][1]) << 16);
            pk.u[1] = (unsigned int)f2b(ot[g][nt][2]) | ((unsigned int)f2b(ot[g][nt][3]) << 16);
            *(bf16x4*)(opw + (g * 16 + r16) * 68 + nt * 16 + quad * 4) = pk.v;
        }
    if (quad == 0) {
#pragma unroll
        for (int g = 0; g < 2; ++g) Ls[ksplit][g * 16 + r16] = al[g][0];
    }
    __syncthreads();

    for (int c = tid; c < 512; c += 256) {
        int q = c >> 4, j4 = (c & 15) * 4;
        float l = Ls[0][q] + Ls[1][q] + Ls[2][q] + Ls[3][q];
        float inv = (l > 0.f) ? (1.f / l) : 0.f;
        float s[4] = {0.f, 0.f, 0.f, 0.f};
#pragma unroll
        for (int sp = 0; sp < 4; ++sp) {
            bf16x4 v = *(const bf16x4*)(Op[sp] + q * 68 + j4);
#pragma unroll
            for (int i = 0; i < 4; ++i)
                s[i] += b2f(((const unsigned short*)&v)[i]);
        }
        bf16x4 pk;
#pragma unroll
        for (int i = 0; i < 4; ++i) pk[i] = (short)f2b(s[i] * inv);
        *(bf16x4*)(y + (((size_t)(b * 2048 + q0 + q)) << 9) + h * 64 + j4) = pk;
    }
}

// ---------------------------------------------------------------------------
// proj: Y(8192x512 bf16) @ wtp^T(512x512 bf16) + b -> fp32 out (tuple split).
// LDS-free direct-global fragments, 128x128 per block.
// ---------------------------------------------------------------------------
__global__ __launch_bounds__(256)
void proj_kernel(const unsigned short* __restrict__ X,
                 const unsigned short* __restrict__ Wt,
                 const float* __restrict__ bias,
                 float* __restrict__ out)
{
    const int m0 = blockIdx.x * 128, n0 = blockIdx.y * 128;
    const int tid = threadIdx.x, lane = tid & 63, w = tid >> 6;
    const int quad = lane >> 4, r16 = lane & 15;
    const int mrow = (w >> 1) * 64, ncol = (w & 1) * 64;

    const f32x4 fz = {0.f, 0.f, 0.f, 0.f};
    f32x4 acc[4][4];
#pragma unroll
    for (int a = 0; a < 4; ++a)
#pragma unroll
        for (int b = 0; b < 4; ++b) acc[a][b] = fz;

    const unsigned short* Ab = X + (size_t)(m0 + mrow + r16) * 512 + quad * 8;
    const unsigned short* Bb = Wt + (size_t)(n0 + ncol + r16) * 512 + quad * 8;

    for (int k0 = 0; k0 < 512; k0 += 32) {
        bf16x8 af[4], bfr[4];
#pragma unroll
        for (int ms = 0; ms < 4; ++ms)
            af[ms] = *(const bf16x8*)(Ab + (size_t)ms * 16 * 512 + k0);
#pragma unroll
        for (int ns = 0; ns < 4; ++ns)
            bfr[ns] = *(const bf16x8*)(Bb + (size_t)ns * 16 * 512 + k0);
#pragma unroll
        for (int ms = 0; ms < 4; ++ms)
#pragma unroll
            for (int ns = 0; ns < 4; ++ns)
                acc[ms][ns] = __builtin_amdgcn_mfma_f32_16x16x32_bf16(
                    af[ms], bfr[ns], acc[ms][ns], 0, 0, 0);
    }

#pragma unroll
    for (int ms = 0; ms < 4; ++ms)
#pragma unroll
        for (int ns = 0; ns < 4; ++ns) {
            int n = n0 + ncol + ns * 16 + r16;
            float bb = bias[n];
#pragma unroll
            for (int i = 0; i < 4; ++i) {
                int m = m0 + mrow + ms * 16 + quad * 4 + i;
                int bi = m >> 11, t = m & 2047;
                float v = acc[ms][ns][i] + bb;
                size_t idx = (t < 1024)
                    ? ((size_t)bi * 1024 + t) * 512 + n
                    : (size_t)2097152 + ((size_t)bi * 1024 + (t - 1024)) * 512 + n;
                out[idx] = v;
            }
        }
}

// ---------------------------------------------------------------------------
extern "C" void kernel_launch(void* const* d_in, const int* in_sizes, int n_in,
                              void* d_out, int out_size, void* d_ws, size_t ws_size,
                              hipStream_t stream)
{
    const float* self_seq  = (const float*)d_in[0];
    const float* cross_seq = (const float*)d_in[1];
    const int*   t_self    = (const int*)d_in[2];
    const int*   t_cross   = (const int*)d_in[3];
    const float* W_self    = (const float*)d_in[4];
    const float* b_self    = (const float*)d_in[5];
    const float* W_cross   = (const float*)d_in[6];
    const float* b_cross   = (const float*)d_in[7];
    const float* W_proj    = (const float*)d_in[8];
    const float* b_proj    = (const float*)d_in[9];
    float* out = (float*)d_out;

    // ws (32 MB): q, k, vt, y (4 x 4,194,304 bf16).
    // d_out slack (16.8 MB) holds xb (8 MB) + wt (3 MB) + wtp (0.5 MB)
    // as scratch until proj overwrites everything.
    unsigned short* qbuf = (unsigned short*)d_ws;
    unsigned short* kbuf = qbuf + 4194304;
    unsigned short* vtb  = kbuf + 4194304;
    unsigned short* ybuf = vtb + 4194304;
    unsigned short* xb   = (unsigned short*)d_out;
    unsigned short* wt   = xb + 4194304;
    unsigned short* wtp  = wt + 1572864;

    prep_kernel<<<dim3(2496), 256, 0, stream>>>(
        self_seq, cross_seq, W_self, W_cross, W_proj, xb, wt, wtp);

    qkv_kernel<<<dim3(32, 12, 2), 256, 0, stream>>>(
        xb, wt, b_self, b_cross, qbuf, kbuf, vtb);

    attn_kernel<<<dim3(2048), 256, 0, stream>>>(
        qbuf, kbuf, vtb, t_self, t_cross, ybuf);

    proj_kernel<<<dim3(64, 4), 256, 0, stream>>>(
        ybuf, wtp, b_proj, out);
}

// Round 7
// 224.008 us; speedup vs baseline: 1.6947x; 1.6947x over previous
//
#include <hip/hip_runtime.h>

// ---------------------------------------------------------------------------
// SelfCrossAttention: B=4, T=1024+1024, d=512, H=8, hd=64. fp32 I/O,
// bf16 MFMA internals.
// prep (X->bf16; W_self/W_cross -> wt[n][k] bf16, q pre-scaled 1/8)
//   -> qkv (LDS 128x128 GEMM; V stored transposed [bh][j][t'] with the key
//           position PERMUTED inside every 32-key window so PV can run K=32)
//   -> attn (S^T flash, 64q/wave, 4-way key split; P exits QK^T directly in
//            the 16x16x32 B-operand layout thanks to the V permutation)
//   -> proj (LDS, fp32 W, fp32 out, tuple split).
// Key-window permutation: pos(r) = (r<16) ? 2r : 2(r-16)+4  (r = key mod 32,
// 4-aligned groups stay contiguous) so B-slot quad*8+j <-> keys
// {4q..4q+3} u {16+4q..16+4q+3} = exactly the order P packs two S-tiles.
// ---------------------------------------------------------------------------

typedef short     bf16x8 __attribute__((ext_vector_type(8)));
typedef short     bf16x4 __attribute__((ext_vector_type(4)));
typedef float     f32x4  __attribute__((ext_vector_type(4)));
typedef int       i32x4  __attribute__((ext_vector_type(4)));

#define DI __device__ __forceinline__

DI unsigned short f2b(float f) {            // fp32 -> bf16 bits, RNE-ish
    union { float f; unsigned int u; } x; x.f = f;
    unsigned int r = x.u + 0x7fffu + ((x.u >> 16) & 1u);
    return (unsigned short)(r >> 16);
}
DI unsigned int fbits(float f) { union { float f; unsigned int u; } x; x.f = f; return x.u; }
DI float bitsf(unsigned int u) { union { unsigned int u; float f; } x; x.u = u; return x.f; }
DI float b2f(unsigned short v) { return bitsf(((unsigned int)v) << 16); }

// ---------------------------------------------------------------------------
// prep: [0,2048): X fp32 -> bf16 flat; [2048,2432): W -> wt[src][n][k] bf16,
// q-section (n<512) scaled by 0.125.
// ---------------------------------------------------------------------------
__global__ __launch_bounds__(256)
void prep_kernel(const float* __restrict__ Xs, const float* __restrict__ Xc,
                 const float* __restrict__ Ws, const float* __restrict__ Wc,
                 unsigned short* __restrict__ xb, unsigned short* __restrict__ wt)
{
    const int bid = blockIdx.x, tid = threadIdx.x;
    if (bid < 2048) {
        int idx = bid * 2048 + tid * 8;
        const float* s = (idx < 2097152) ? (Xs + idx) : (Xc + idx - 2097152);
        f32x4 a0 = *(const f32x4*)s;
        f32x4 a1 = *(const f32x4*)(s + 4);
        bf16x8 v;
#pragma unroll
        for (int j = 0; j < 4; ++j) {
            ((unsigned short*)&v)[j]     = f2b(a0[j]);
            ((unsigned short*)&v)[4 + j] = f2b(a1[j]);
        }
        *(bf16x8*)(xb + idx) = v;
        return;
    }
    __shared__ unsigned short Tt[64 * 72];
    int tj  = bid - 2048;
    int src = tj >= 192;  tj -= src * 192;
    int k0  = (tj / 24) * 64;
    int n0  = (tj % 24) * 64;
    const float* W = src ? Wc : Ws;
    float sc = (n0 < 512) ? 0.125f : 1.0f;
#pragma unroll
    for (int r = 0; r < 4; ++r) {
        int g  = tid + r * 256;
        int kr = g >> 4, nc4 = (g & 15) * 4;
        f32x4 v = *(const f32x4*)(W + (size_t)(k0 + kr) * 1536 + n0 + nc4);
#pragma unroll
        for (int u = 0; u < 4; ++u)
            Tt[(nc4 + u) * 72 + kr] = f2b(v[u] * sc);
    }
    __syncthreads();
#pragma unroll
    for (int r = 0; r < 2; ++r) {
        int c = tid + r * 256;
        int nl = c >> 3, k8 = (c & 7) * 8;
        *(bf16x8*)(wt + (size_t)src * 786432 + (size_t)(n0 + nl) * 512 + k0 + k8) =
            *(const bf16x8*)(Tt + nl * 72 + k8);
    }
}

// ---------------------------------------------------------------------------
// QKV: xb @ wt^T + bias. 128x128 tile, 256 thr, LDS-staged (R5 structure).
// q/k -> [bh][t][j]; v -> vt[bh][j][t'] with the 32-window key permutation.
// ---------------------------------------------------------------------------
__global__ __launch_bounds__(256)
void qkv_kernel(const unsigned short* __restrict__ xb,
                const unsigned short* __restrict__ wt,
                const float* __restrict__ bs, const float* __restrict__ bc,
                unsigned short* __restrict__ qb, unsigned short* __restrict__ kb,
                unsigned short* __restrict__ vtb)
{
    const int src = blockIdx.z;
    const int m0 = blockIdx.x * 128, n0 = blockIdx.y * 128;
    const float* bias = src ? bc : bs;
    const unsigned short* X = xb + (size_t)src * 2097152;
    const unsigned short* W = wt + (size_t)src * 786432;

    __shared__ unsigned short As[128 * 40];
    __shared__ unsigned short Bs[128 * 40];

    const int tid = threadIdx.x, lane = tid & 63, w = tid >> 6;
    const int quad = lane >> 4, r16 = lane & 15;
    const int mrow = (w >> 1) * 64, ncol = (w & 1) * 64;

    const f32x4 fz = {0.f, 0.f, 0.f, 0.f};
    f32x4 acc[4][4];
#pragma unroll
    for (int a = 0; a < 4; ++a)
#pragma unroll
        for (int b = 0; b < 4; ++b) acc[a][b] = fz;

    const int srow = tid >> 2, sk8 = (tid & 3) * 8;

    for (int k0 = 0; k0 < 512; k0 += 32) {
#pragma unroll
        for (int r = 0; r < 2; ++r) {
            int row = srow + r * 64;
            bf16x8 av = *(const bf16x8*)(X + (size_t)(m0 + row) * 512 + k0 + sk8);
            bf16x8 bv = *(const bf16x8*)(W + (size_t)(n0 + row) * 512 + k0 + sk8);
            *(bf16x8*)(As + row * 40 + sk8) = av;
            *(bf16x8*)(Bs + row * 40 + (sk8 ^ (((row >> 3) & 3) * 8))) = bv;
        }
        __syncthreads();

        bf16x8 af[4], bfr[4];
#pragma unroll
        for (int ms = 0; ms < 4; ++ms)
            af[ms] = *(const bf16x8*)(As + (mrow + ms * 16 + r16) * 40 + quad * 8);
#pragma unroll
        for (int ns = 0; ns < 4; ++ns) {
            int n = ncol + ns * 16 + r16;
            bfr[ns] = *(const bf16x8*)(Bs + n * 40 + ((quad * 8) ^ (((n >> 3) & 3) * 8)));
        }
#pragma unroll
        for (int ms = 0; ms < 4; ++ms)
#pragma unroll
            for (int ns = 0; ns < 4; ++ns)
                acc[ms][ns] = __builtin_amdgcn_mfma_f32_16x16x32_bf16(
                    af[ms], bfr[ns], acc[ms][ns], 0, 0, 0);
        __syncthreads();
    }

#pragma unroll
    for (int ms = 0; ms < 4; ++ms)
#pragma unroll
        for (int ns = 0; ns < 4; ++ns) {
            int n = n0 + ncol + ns * 16 + r16;
            int sec = n >> 9, col = n & 511;
            int hh = col >> 6, j = col & 63;
            float bb = bias[n] * ((sec == 0) ? 0.125f : 1.0f);
            int mb = m0 + mrow + ms * 16 + quad * 4;
            int bi = mb >> 10, tg0 = (mb & 1023) + (src << 10);
            if (sec == 2) {                 // V: transposed + window-permuted
                bf16x4 pk;
#pragma unroll
                for (int i = 0; i < 4; ++i)
                    pk[i] = (short)f2b(acc[ms][ns][i] + bb);
                int r = tg0 & 31;           // 4-aligned
                int pos = (r < 16) ? (r << 1) : (((r - 16) << 1) + 4);
                int tgp = (tg0 & ~31) + pos;
                *(bf16x4*)(vtb + (((size_t)(bi * 8 + hh) * 64 + j) << 11) + tgp) = pk;
            } else {
                unsigned short* dst = (sec == 0) ? qb : kb;
#pragma unroll
                for (int i = 0; i < 4; ++i)
                    dst[(((size_t)(bi * 8 + hh) * 2048 + tg0 + i) << 6) + j] =
                        f2b(acc[ms][ns][i] + bb);
            }
        }
}

// ---------------------------------------------------------------------------
// attn: S^T flash. Block 256 thr = 4 waves; block = 64 queries of one bh;
// wave = all 64 q x 8 K-tiles (4-way key split). Per 32-key window: two
// S-tiles -> exp -> truncate-pack straight into the 16x16x32 B-operand
// (enabled by the permuted V layout); PV = K=32 MFMAs with b128 V loads.
// Partials merged via LDS. Grid swizzled: each XCD sees 4 bh.
// ---------------------------------------------------------------------------
__global__ __launch_bounds__(256)
void attn_kernel(const unsigned short* __restrict__ qb,
                 const unsigned short* __restrict__ kb,
                 const unsigned short* __restrict__ vt,
                 const int* __restrict__ t_self, const int* __restrict__ t_cross,
                 unsigned short* __restrict__ y)
{
    const int bid = blockIdx.x;
    const int bh = ((bid & 7) << 2) | ((bid >> 3) & 3);   // XCD-local bh group
    const int qt = bid >> 5;
    const int b = bh >> 3, h = bh & 7;
    const int tid = threadIdx.x, ksplit = tid >> 6, lane = tid & 63;
    const int quad = lane >> 4, r16 = lane & 15;

    const unsigned short* Q = qb + (size_t)bh * 131072;
    const unsigned short* K = kb + (size_t)bh * 131072;
    const unsigned short* V = vt + (size_t)bh * 131072;
    const int* tsb = t_self + b * 1024;
    const int* tcb = t_cross + b * 1024;

    __shared__ unsigned short Op[4][64 * 68];   // bf16 partial O^T per split
    __shared__ float Ls[4][64];

    const int q0 = qt * 64;

    bf16x8 qf[4][2];
#pragma unroll
    for (int g = 0; g < 4; ++g)
#pragma unroll
        for (int ks = 0; ks < 2; ++ks)
            qf[g][ks] = *(const bf16x8*)(Q + (size_t)(q0 + g * 16 + r16) * 64
                                           + ks * 32 + quad * 8);

    const int* tqp = (qt < 16) ? (tsb + qt * 64) : (tcb + (qt - 16) * 64);
    int tq[4];
#pragma unroll
    for (int g = 0; g < 4; ++g) tq[g] = tqp[g * 16 + r16];

    const f32x4 fz = {0.f, 0.f, 0.f, 0.f};
    f32x4 ot[4][4];
    float rs[4] = {0.f, 0.f, 0.f, 0.f};
#pragma unroll
    for (int g = 0; g < 4; ++g)
#pragma unroll
        for (int nt = 0; nt < 4; ++nt) ot[g][nt] = fz;

    for (int it = 0; it < 8; ++it) {
        const int kt = ksplit * 8 + it;
        const int krow = kt * 64;
        const int* tkp = (kt < 16) ? (tsb + krow) : (tcb + krow - 1024);

#pragma unroll
        for (int c = 0; c < 2; ++c) {               // 32-key windows
            const int kw = krow + c * 32;
            i32x4 tk0 = *(const i32x4*)(tkp + c * 32 + quad * 4);
            i32x4 tk1 = *(const i32x4*)(tkp + c * 32 + 16 + quad * 4);
            const unsigned short* kr0 = K + (size_t)(kw + r16) * 64 + quad * 8;
            const unsigned short* kr1 = K + (size_t)(kw + 16 + r16) * 64 + quad * 8;
            bf16x8 ka00 = *(const bf16x8*)(kr0);
            bf16x8 ka01 = *(const bf16x8*)(kr0 + 32);
            bf16x8 ka10 = *(const bf16x8*)(kr1);
            bf16x8 ka11 = *(const bf16x8*)(kr1 + 32);

            bf16x8 pf[4];
#pragma unroll
            for (int g = 0; g < 4; ++g) {
                f32x4 s0 = fz, s1 = fz;
                s0 = __builtin_amdgcn_mfma_f32_16x16x32_bf16(ka00, qf[g][0], s0, 0, 0, 0);
                s0 = __builtin_amdgcn_mfma_f32_16x16x32_bf16(ka01, qf[g][1], s0, 0, 0, 0);
                s1 = __builtin_amdgcn_mfma_f32_16x16x32_bf16(ka10, qf[g][0], s1, 0, 0, 0);
                s1 = __builtin_amdgcn_mfma_f32_16x16x32_bf16(ka11, qf[g][1], s1, 0, 0, 0);
                unsigned int u[8];
#pragma unroll
                for (int i = 0; i < 4; ++i) {
                    float a0 = (tq[g] >= tk0[i]) ? s0[i] : -1e9f;   // select ARG
                    float a1 = (tq[g] >= tk1[i]) ? s1[i] : -1e9f;
                    u[i]     = fbits(__expf(fminf(a0, 80.f))) & 0xFFFF0000u;
                    u[4 + i] = fbits(__expf(fminf(a1, 80.f))) & 0xFFFF0000u;
                }
#pragma unroll
                for (int i = 0; i < 8; ++i) rs[g] += bitsf(u[i]);   // l == sum stored P
                union { unsigned int d[4]; bf16x8 v; } pu;          // truncate-pack
                pu.d[0] = (u[0] >> 16) | u[1];
                pu.d[1] = (u[2] >> 16) | u[3];
                pu.d[2] = (u[4] >> 16) | u[5];
                pu.d[3] = (u[6] >> 16) | u[7];
                pf[g] = pu.v;
            }

            // O^T += V^T · P^T  (K=32, b128 V loads from permuted layout)
#pragma unroll
            for (int nt = 0; nt < 4; ++nt) {
                bf16x8 va = *(const bf16x8*)(V + (size_t)(nt * 16 + r16) * 2048
                                               + kw + quad * 8);
                ot[0][nt] = __builtin_amdgcn_mfma_f32_16x16x32_bf16(va, pf[0], ot[0][nt], 0, 0, 0);
                ot[1][nt] = __builtin_amdgcn_mfma_f32_16x16x32_bf16(va, pf[1], ot[1][nt], 0, 0, 0);
                ot[2][nt] = __builtin_amdgcn_mfma_f32_16x16x32_bf16(va, pf[2], ot[2][nt], 0, 0, 0);
                ot[3][nt] = __builtin_amdgcn_mfma_f32_16x16x32_bf16(va, pf[3], ot[3][nt], 0, 0, 0);
            }
        }
    }

    // partial-l: sum across the 4 quads (keys) for each query column
#pragma unroll
    for (int g = 0; g < 4; ++g) {
        rs[g] += __shfl_xor(rs[g], 16);
        rs[g] += __shfl_xor(rs[g], 32);
    }

    // write partials (bf16 O^T, fp32 l) and merge
    unsigned short* opw = Op[ksplit];
#pragma unroll
    for (int g = 0; g < 4; ++g)
#pragma unroll
        for (int nt = 0; nt < 4; ++nt) {
            union { unsigned int u[2]; bf16x4 v; } pk;
            pk.u[0] = (unsigned int)f2b(ot[g][nt][0]) | ((unsigned int)f2b(ot[g][nt][1]) << 16);
            pk.u[1] = (unsigned int)f2b(ot[g][nt][2]) | ((unsigned int)f2b(ot[g][nt][3]) << 16);
            *(bf16x4*)(opw + (g * 16 + r16) * 68 + nt * 16 + quad * 4) = pk.v;
        }
    if (quad == 0) {
#pragma unroll
        for (int g = 0; g < 4; ++g) Ls[ksplit][g * 16 + r16] = rs[g];
    }
    __syncthreads();

    for (int c = tid; c < 1024; c += 256) {
        int q = c >> 4, j4 = (c & 15) * 4;
        float l = Ls[0][q] + Ls[1][q] + Ls[2][q] + Ls[3][q];
        float inv = (l > 0.f) ? (1.f / l) : 0.f;
        float s[4] = {0.f, 0.f, 0.f, 0.f};
#pragma unroll
        for (int sp = 0; sp < 4; ++sp) {
            bf16x4 v = *(const bf16x4*)(Op[sp] + q * 68 + j4);
#pragma unroll
            for (int i = 0; i < 4; ++i)
                s[i] += b2f(((const unsigned short*)&v)[i]);
        }
        bf16x4 pk;
#pragma unroll
        for (int i = 0; i < 4; ++i) pk[i] = (short)f2b(s[i] * inv);
        *(bf16x4*)(y + (((size_t)(b * 2048 + q0 + q)) << 9) + h * 64 + j4) = pk;
    }
}

// ---------------------------------------------------------------------------
// proj: Y(8192x512 bf16) @ W_proj(512x512 fp32) + b -> fp32 out (tuple split)
// LDS-staged 64x64 tiles (R5 structure).
// ---------------------------------------------------------------------------
__global__ __launch_bounds__(256)
void proj_kernel(const unsigned short* __restrict__ X,
                 const float* __restrict__ W, const float* __restrict__ bias,
                 float* __restrict__ out)
{
    const int m0 = blockIdx.x * 64, n0 = blockIdx.y * 64;
    __shared__ unsigned short As[64 * 40];
    __shared__ unsigned short Bt[64 * 40];

    const int tid = threadIdx.x, lane = tid & 63, w = tid >> 6;
    const int quad = lane >> 4, r16 = lane & 15;
    const int mrow = (w >> 1) * 32, ncol = (w & 1) * 32;

    const f32x4 fz = {0.f, 0.f, 0.f, 0.f};
    f32x4 acc[2][2];
    acc[0][0] = fz; acc[0][1] = fz; acc[1][0] = fz; acc[1][1] = fz;

    const int a_row = tid >> 2, a_k = (tid & 3) * 8;
    const int b_k = tid >> 3, b_n8 = (tid & 7) * 8;

    for (int k0 = 0; k0 < 512; k0 += 32) {
        bf16x8 av = *(const bf16x8*)(X + (size_t)(m0 + a_row) * 512 + k0 + a_k);
        const float* bp = W + (size_t)(k0 + b_k) * 512 + n0 + b_n8;
        f32x4 b0 = *(const f32x4*)bp;
        f32x4 b1 = *(const f32x4*)(bp + 4);
        *(bf16x8*)(As + a_row * 40 + a_k) = av;
#pragma unroll
        for (int jj = 0; jj < 8; ++jj) {
            int n = b_n8 + jj;
            int c = ((n >> 3) & 3) * 8;
            Bt[n * 40 + (b_k ^ c)] = f2b((jj < 4) ? b0[jj & 3] : b1[jj & 3]);
        }
        __syncthreads();

        bf16x8 af[2], bfr[2];
#pragma unroll
        for (int ms = 0; ms < 2; ++ms)
            af[ms] = *(const bf16x8*)(As + (mrow + ms * 16 + r16) * 40 + quad * 8);
#pragma unroll
        for (int ns = 0; ns < 2; ++ns) {
            int n = ncol + ns * 16 + r16;
            bfr[ns] = *(const bf16x8*)(Bt + n * 40 + ((quad * 8) ^ (((n >> 3) & 3) * 8)));
        }
#pragma unroll
        for (int ms = 0; ms < 2; ++ms)
#pragma unroll
            for (int ns = 0; ns < 2; ++ns)
                acc[ms][ns] = __builtin_amdgcn_mfma_f32_16x16x32_bf16(
                    af[ms], bfr[ns], acc[ms][ns], 0, 0, 0);
        __syncthreads();
    }

#pragma unroll
    for (int ms = 0; ms < 2; ++ms)
#pragma unroll
        for (int ns = 0; ns < 2; ++ns) {
            int n = n0 + ncol + ns * 16 + r16;
            float bb = bias[n];
#pragma unroll
            for (int i = 0; i < 4; ++i) {
                int m = m0 + mrow + ms * 16 + quad * 4 + i;
                int bi = m >> 11, t = m & 2047;
                float v = acc[ms][ns][i] + bb;
                size_t idx = (t < 1024)
                    ? ((size_t)bi * 1024 + t) * 512 + n
                    : (size_t)2097152 + ((size_t)bi * 1024 + (t - 1024)) * 512 + n;
                out[idx] = v;
            }
        }
}

// ---------------------------------------------------------------------------
extern "C" void kernel_launch(void* const* d_in, const int* in_sizes, int n_in,
                              void* d_out, int out_size, void* d_ws, size_t ws_size,
                              hipStream_t stream)
{
    const float* self_seq  = (const float*)d_in[0];
    const float* cross_seq = (const float*)d_in[1];
    const int*   t_self    = (const int*)d_in[2];
    const int*   t_cross   = (const int*)d_in[3];
    const float* W_self    = (const float*)d_in[4];
    const float* b_self    = (const float*)d_in[5];
    const float* W_cross   = (const float*)d_in[6];
    const float* b_cross   = (const float*)d_in[7];
    const float* W_proj    = (const float*)d_in[8];
    const float* b_proj    = (const float*)d_in[9];
    float* out = (float*)d_out;

    // ws (32 MB): q, k, vt, y (4 x 4,194,304 bf16). d_out slack holds xb/wt.
    unsigned short* qbuf = (unsigned short*)d_ws;
    unsigned short* kbuf = qbuf + 4194304;
    unsigned short* vtb  = kbuf + 4194304;
    unsigned short* ybuf = vtb + 4194304;
    unsigned short* xb   = (unsigned short*)d_out;   // scratch until proj
    unsigned short* wt   = xb + 4194304;

    prep_kernel<<<dim3(2432), 256, 0, stream>>>(
        self_seq, cross_seq, W_self, W_cross, xb, wt);

    qkv_kernel<<<dim3(32, 12, 2), 256, 0, stream>>>(
        xb, wt, b_self, b_cross, qbuf, kbuf, vtb);

    attn_kernel<<<dim3(1024), 256, 0, stream>>>(
        qbuf, kbuf, vtb, t_self, t_cross, ybuf);

    proj_kernel<<<dim3(128, 8), 256, 0, stream>>>(
        ybuf, W_proj, b_proj, out);
}

// Round 8
// 211.293 us; speedup vs baseline: 1.7967x; 1.0602x over previous
//
#include <hip/hip_runtime.h>

// ---------------------------------------------------------------------------
// SelfCrossAttention: B=4, T=1024+1024, d=512, H=8, hd=64. fp32 I/O,
// bf16 MFMA internals.
// prep (X->bf16; W_self/W_cross -> wt[n][k], q section pre-scaled by
//       0.125*log2(e) so attention runs in exp2 domain; W_proj -> wtp[n][k])
//   -> qkv (128x128 LDS GEMM staged via global_load_lds width=16, unpadded
//           stride-32 LDS; V stored transposed+window-permuted for K=32 PV)
//   -> attn (S^T flash, 64q/wave, 4-way key split; exp2 softmax, l summed by
//            ones-A MFMA from the SAME packed P regs)
//   -> proj (same glds GEMM, bf16 wtp, fp32 out, tuple split).
// ---------------------------------------------------------------------------

typedef short     bf16x8 __attribute__((ext_vector_type(8)));
typedef short     bf16x4 __attribute__((ext_vector_type(4)));
typedef float     f32x4  __attribute__((ext_vector_type(4)));
typedef int       i32x4  __attribute__((ext_vector_type(4)));

#define DI __device__ __forceinline__

DI unsigned short f2b(float f) {            // fp32 -> bf16 bits, RNE-ish
    union { float f; unsigned int u; } x; x.f = f;
    unsigned int r = x.u + 0x7fffu + ((x.u >> 16) & 1u);
    return (unsigned short)(r >> 16);
}
DI unsigned int fbits(float f) { union { float f; unsigned int u; } x; x.f = f; return x.u; }
DI float bitsf(unsigned int u) { union { unsigned int u; float f; } x; x.u = u; return x.f; }
DI float b2f(unsigned short v) { return bitsf(((unsigned int)v) << 16); }

DI void glds16(const unsigned short* g, unsigned short* l) {   // 16B global->LDS
    __builtin_amdgcn_global_load_lds(
        (const __attribute__((address_space(1))) void*)g,
        (__attribute__((address_space(3))) void*)l, 16, 0, 0);
}

#define QSCALE 0.18033688011112042f   // 0.125 * log2(e): exp2-domain scores

// ---------------------------------------------------------------------------
// prep: [0,2048): X fp32 -> bf16 flat.
//       [2048,2432): W_self/W_cross -> wt[src][n][k], q-section * QSCALE
//       [2432,2496): W_proj -> wtp[n][k]
// ---------------------------------------------------------------------------
__global__ __launch_bounds__(256)
void prep_kernel(const float* __restrict__ Xs, const float* __restrict__ Xc,
                 const float* __restrict__ Ws, const float* __restrict__ Wc,
                 const float* __restrict__ Wp,
                 unsigned short* __restrict__ xb, unsigned short* __restrict__ wt,
                 unsigned short* __restrict__ wtp)
{
    const int bid = blockIdx.x, tid = threadIdx.x;
    if (bid < 2048) {
        int idx = bid * 2048 + tid * 8;
        const float* s = (idx < 2097152) ? (Xs + idx) : (Xc + idx - 2097152);
        f32x4 a0 = *(const f32x4*)s;
        f32x4 a1 = *(const f32x4*)(s + 4);
        bf16x8 v;
#pragma unroll
        for (int j = 0; j < 4; ++j) {
            ((unsigned short*)&v)[j]     = f2b(a0[j]);
            ((unsigned short*)&v)[4 + j] = f2b(a1[j]);
        }
        *(bf16x8*)(xb + idx) = v;
        return;
    }
    __shared__ unsigned short Tt[64 * 72];
    const float* W;
    unsigned short* dst;
    int k0, n0, ldn;
    float sc = 1.0f;
    if (bid < 2432) {
        int tj  = bid - 2048;
        int src = tj >= 192;  tj -= src * 192;
        k0  = (tj / 24) * 64;
        n0  = (tj % 24) * 64;
        W   = src ? Wc : Ws;
        ldn = 1536;
        dst = wt + (size_t)src * 786432;
        if (n0 < 512) sc = QSCALE;
    } else {
        int tj = bid - 2432;
        k0  = (tj >> 3) * 64;
        n0  = (tj & 7) * 64;
        W   = Wp;
        ldn = 512;
        dst = wtp;
    }
#pragma unroll
    for (int r = 0; r < 4; ++r) {
        int g  = tid + r * 256;
        int kr = g >> 4, nc4 = (g & 15) * 4;
        f32x4 v = *(const f32x4*)(W + (size_t)(k0 + kr) * ldn + n0 + nc4);
#pragma unroll
        for (int u = 0; u < 4; ++u)
            Tt[(nc4 + u) * 72 + kr] = f2b(v[u] * sc);
    }
    __syncthreads();
#pragma unroll
    for (int r = 0; r < 2; ++r) {
        int c = tid + r * 256;
        int nl = c >> 3, k8 = (c & 7) * 8;
        *(bf16x8*)(dst + (size_t)(n0 + nl) * 512 + k0 + k8) =
            *(const bf16x8*)(Tt + nl * 72 + k8);
    }
}

// ---------------------------------------------------------------------------
// QKV: xb @ wt^T + bias. 128x128 tile, 256 thr, glds-staged unpadded LDS.
// q/k -> [bh][t][j]; v -> vt[bh][j][t'] with the 32-window key permutation.
// ---------------------------------------------------------------------------
__global__ __launch_bounds__(256)
void qkv_kernel(const unsigned short* __restrict__ xb,
                const unsigned short* __restrict__ wt,
                const float* __restrict__ bs, const float* __restrict__ bc,
                unsigned short* __restrict__ qb, unsigned short* __restrict__ kb,
                unsigned short* __restrict__ vtb)
{
    const int src = blockIdx.z;
    const int m0 = blockIdx.x * 128, n0 = blockIdx.y * 128;
    const float* bias = src ? bc : bs;
    const unsigned short* X = xb + (size_t)src * 2097152;
    const unsigned short* W = wt + (size_t)src * 786432;

    __shared__ unsigned short As[128 * 32];
    __shared__ unsigned short Bs[128 * 32];

    const int tid = threadIdx.x, lane = tid & 63, w = tid >> 6;
    const int quad = lane >> 4, r16 = lane & 15;
    const int mrow = (w >> 1) * 64, ncol = (w & 1) * 64;

    const f32x4 fz = {0.f, 0.f, 0.f, 0.f};
    f32x4 acc[4][4];
#pragma unroll
    for (int a = 0; a < 4; ++a)
#pragma unroll
        for (int b = 0; b < 4; ++b) acc[a][b] = fz;

    // glds staging: chunk ci covers rows [ci*16, ci*16+16); lane -> row/koff
    const int ci   = w << 1;
    const int rofs = lane >> 2, kofs = (lane & 3) * 8;
    const unsigned short* gA = X + (size_t)(m0 + ci * 16 + rofs) * 512 + kofs;
    const unsigned short* gB = W + (size_t)(n0 + ci * 16 + rofs) * 512 + kofs;
    unsigned short* lA = As + ci * 512 + lane * 8;
    unsigned short* lB = Bs + ci * 512 + lane * 8;

    for (int k0 = 0; k0 < 512; k0 += 32) {
        glds16(gA + k0, lA);
        glds16(gA + 16 * 512 + k0, lA + 512);
        glds16(gB + k0, lB);
        glds16(gB + 16 * 512 + k0, lB + 512);
        __syncthreads();

        bf16x8 af[4], bfr[4];
#pragma unroll
        for (int ms = 0; ms < 4; ++ms)
            af[ms] = *(const bf16x8*)(As + (mrow + ms * 16 + r16) * 32 + quad * 8);
#pragma unroll
        for (int ns = 0; ns < 4; ++ns)
            bfr[ns] = *(const bf16x8*)(Bs + (ncol + ns * 16 + r16) * 32 + quad * 8);
#pragma unroll
        for (int ms = 0; ms < 4; ++ms)
#pragma unroll
            for (int ns = 0; ns < 4; ++ns)
                acc[ms][ns] = __builtin_amdgcn_mfma_f32_16x16x32_bf16(
                    af[ms], bfr[ns], acc[ms][ns], 0, 0, 0);
        __syncthreads();
    }

#pragma unroll
    for (int ms = 0; ms < 4; ++ms)
#pragma unroll
        for (int ns = 0; ns < 4; ++ns) {
            int n = n0 + ncol + ns * 16 + r16;
            int sec = n >> 9, col = n & 511;
            int hh = col >> 6, j = col & 63;
            float bb = bias[n] * ((sec == 0) ? QSCALE : 1.0f);
            int mb = m0 + mrow + ms * 16 + quad * 4;
            int bi = mb >> 10, tg0 = (mb & 1023) + (src << 10);
            if (sec == 2) {                 // V: transposed + window-permuted
                bf16x4 pk;
#pragma unroll
                for (int i = 0; i < 4; ++i)
                    pk[i] = (short)f2b(acc[ms][ns][i] + bb);
                int r = tg0 & 31;           // 4-aligned
                int pos = (r < 16) ? (r << 1) : (((r - 16) << 1) + 4);
                int tgp = (tg0 & ~31) + pos;
                *(bf16x4*)(vtb + (((size_t)(bi * 8 + hh) * 64 + j) << 11) + tgp) = pk;
            } else {
                unsigned short* dst = (sec == 0) ? qb : kb;
#pragma unroll
                for (int i = 0; i < 4; ++i)
                    dst[(((size_t)(bi * 8 + hh) * 2048 + tg0 + i) << 6) + j] =
                        f2b(acc[ms][ns][i] + bb);
            }
        }
}

// ---------------------------------------------------------------------------
// attn: S^T flash, exp2 domain. Block 256 thr = 4 waves; block = 64 queries
// of one bh; wave = all 64 q x 8 K-tiles (4-way key split). Per 32-key
// window: two S-tiles -> exp2 -> perm-pack (truncating) -> K=32 PV;
// l summed by ones-A MFMA from the same packed P. Grid: XCD sees 4 bh.
// ---------------------------------------------------------------------------
__global__ __launch_bounds__(256)
void attn_kernel(const unsigned short* __restrict__ qb,
                 const unsigned short* __restrict__ kb,
                 const unsigned short* __restrict__ vt,
                 const int* __restrict__ t_self, const int* __restrict__ t_cross,
                 unsigned short* __restrict__ y)
{
    const int bid = blockIdx.x;
    const int bh = ((bid & 7) << 2) | ((bid >> 3) & 3);   // XCD-local bh group
    const int qt = bid >> 5;
    const int b = bh >> 3, h = bh & 7;
    const int tid = threadIdx.x, ksplit = tid >> 6, lane = tid & 63;
    const int quad = lane >> 4, r16 = lane & 15;

    const unsigned short* Q = qb + (size_t)bh * 131072;
    const unsigned short* K = kb + (size_t)bh * 131072;
    const unsigned short* V = vt + (size_t)bh * 131072;
    const int* tsb = t_self + b * 1024;
    const int* tcb = t_cross + b * 1024;

    __shared__ unsigned short Op[4][64 * 68];   // bf16 partial O^T per split
    __shared__ float Ls[4][64];

    const int q0 = qt * 64;

    bf16x8 qf[4][2];
#pragma unroll
    for (int g = 0; g < 4; ++g)
#pragma unroll
        for (int ks = 0; ks < 2; ++ks)
            qf[g][ks] = *(const bf16x8*)(Q + (size_t)(q0 + g * 16 + r16) * 64
                                           + ks * 32 + quad * 8);

    const int* tqp = (qt < 16) ? (tsb + qt * 64) : (tcb + (qt - 16) * 64);
    int tq[4];
#pragma unroll
    for (int g = 0; g < 4; ++g) tq[g] = tqp[g * 16 + r16];

    const f32x4 fz = {0.f, 0.f, 0.f, 0.f};
    f32x4 ot[4][4], al[4];
#pragma unroll
    for (int g = 0; g < 4; ++g) {
        al[g] = fz;
#pragma unroll
        for (int nt = 0; nt < 4; ++nt) ot[g][nt] = fz;
    }
    const bf16x8 ones = {(short)0x3F80, (short)0x3F80, (short)0x3F80, (short)0x3F80,
                         (short)0x3F80, (short)0x3F80, (short)0x3F80, (short)0x3F80};

    for (int it = 0; it < 8; ++it) {
        const int kt = ksplit * 8 + it;
        const int krow = kt * 64;
        const int* tkp = (kt < 16) ? (tsb + krow) : (tcb + krow - 1024);

#pragma unroll
        for (int c = 0; c < 2; ++c) {               // 32-key windows
            const int kw = krow + c * 32;
            i32x4 tk0 = *(const i32x4*)(tkp + c * 32 + quad * 4);
            i32x4 tk1 = *(const i32x4*)(tkp + c * 32 + 16 + quad * 4);
            const unsigned short* kr0 = K + (size_t)(kw + r16) * 64 + quad * 8;
            const unsigned short* kr1 = K + (size_t)(kw + 16 + r16) * 64 + quad * 8;
            bf16x8 ka00 = *(const bf16x8*)(kr0);
            bf16x8 ka01 = *(const bf16x8*)(kr0 + 32);
            bf16x8 ka10 = *(const bf16x8*)(kr1);
            bf16x8 ka11 = *(const bf16x8*)(kr1 + 32);

            bf16x8 pf[4];
#pragma unroll
            for (int g = 0; g < 4; ++g) {
                f32x4 s0 = fz, s1 = fz;
                s0 = __builtin_amdgcn_mfma_f32_16x16x32_bf16(ka00, qf[g][0], s0, 0, 0, 0);
                s0 = __builtin_amdgcn_mfma_f32_16x16x32_bf16(ka01, qf[g][1], s0, 0, 0, 0);
                s1 = __builtin_amdgcn_mfma_f32_16x16x32_bf16(ka10, qf[g][0], s1, 0, 0, 0);
                s1 = __builtin_amdgcn_mfma_f32_16x16x32_bf16(ka11, qf[g][1], s1, 0, 0, 0);
                float e[8];
#pragma unroll
                for (int i = 0; i < 4; ++i) {
                    float a0 = (tq[g] >= tk0[i]) ? s0[i] : -1e9f;   // select ARG
                    float a1 = (tq[g] >= tk1[i]) ? s1[i] : -1e9f;
                    e[i]     = __builtin_amdgcn_exp2f(a0);          // exp2 domain
                    e[4 + i] = __builtin_amdgcn_exp2f(a1);
                }
                union { unsigned int d[4]; bf16x8 v; } pu;          // truncate-pack
                pu.d[0] = __builtin_amdgcn_perm(fbits(e[1]), fbits(e[0]), 0x07060302u);
                pu.d[1] = __builtin_amdgcn_perm(fbits(e[3]), fbits(e[2]), 0x07060302u);
                pu.d[2] = __builtin_amdgcn_perm(fbits(e[5]), fbits(e[4]), 0x07060302u);
                pu.d[3] = __builtin_amdgcn_perm(fbits(e[7]), fbits(e[6]), 0x07060302u);
                pf[g] = pu.v;
                // l partial from the SAME stored-precision P (ones-A MFMA)
                al[g] = __builtin_amdgcn_mfma_f32_16x16x32_bf16(ones, pf[g], al[g], 0, 0, 0);
            }

            // O^T += V^T · P^T  (K=32, b128 V loads from permuted layout)
#pragma unroll
            for (int nt = 0; nt < 4; ++nt) {
                bf16x8 va = *(const bf16x8*)(V + (size_t)(nt * 16 + r16) * 2048
                                               + kw + quad * 8);
                ot[0][nt] = __builtin_amdgcn_mfma_f32_16x16x32_bf16(va, pf[0], ot[0][nt], 0, 0, 0);
                ot[1][nt] = __builtin_amdgcn_mfma_f32_16x16x32_bf16(va, pf[1], ot[1][nt], 0, 0, 0);
                ot[2][nt] = __builtin_amdgcn_mfma_f32_16x16x32_bf16(va, pf[2], ot[2][nt], 0, 0, 0);
                ot[3][nt] = __builtin_amdgcn_mfma_f32_16x16x32_bf16(va, pf[3], ot[3][nt], 0, 0, 0);
            }
        }
    }

    // write partials (bf16 O^T, fp32 l) and merge
    unsigned short* opw = Op[ksplit];
#pragma unroll
    for (int g = 0; g < 4; ++g)
#pragma unroll
        for (int nt = 0; nt < 4; ++nt) {
            union { unsigned int u[2]; bf16x4 v; } pk;
            pk.u[0] = (unsigned int)f2b(ot[g][nt][0]) | ((unsigned int)f2b(ot[g][nt][1]) << 16);
            pk.u[1] = (unsigned int)f2b(ot[g][nt][2]) | ((unsigned int)f2b(ot[g][nt][3]) << 16);
            *(bf16x4*)(opw + (g * 16 + r16) * 68 + nt * 16 + quad * 4) = pk.v;
        }
    if (quad == 0) {
#pragma unroll
        for (int g = 0; g < 4; ++g) Ls[ksplit][g * 16 + r16] = al[g][0];
    }
    __syncthreads();

    for (int c = tid; c < 1024; c += 256) {
        int q = c >> 4, j4 = (c & 15) * 4;
        float l = Ls[0][q] + Ls[1][q] + Ls[2][q] + Ls[3][q];
        float inv = (l > 0.f) ? (1.f / l) : 0.f;
        float s[4] = {0.f, 0.f, 0.f, 0.f};
#pragma unroll
        for (int sp = 0; sp < 4; ++sp) {
            bf16x4 v = *(const bf16x4*)(Op[sp] + q * 68 + j4);
#pragma unroll
            for (int i = 0; i < 4; ++i)
                s[i] += b2f(((const unsigned short*)&v)[i]);
        }
        bf16x4 pk;
#pragma unroll
        for (int i = 0; i < 4; ++i) pk[i] = (short)f2b(s[i] * inv);
        *(bf16x4*)(y + (((size_t)(b * 2048 + q0 + q)) << 9) + h * 64 + j4) = pk;
    }
}

// ---------------------------------------------------------------------------
// proj: Y(8192x512 bf16) @ wtp^T(512x512 bf16) + b -> fp32 out (tuple split).
// Same glds-staged 128x128 GEMM structure as qkv.
// ---------------------------------------------------------------------------
__global__ __launch_bounds__(256)
void proj_kernel(const unsigned short* __restrict__ X,
                 const unsigned short* __restrict__ Wt,
                 const float* __restrict__ bias,
                 float* __restrict__ out)
{
    const int m0 = blockIdx.x * 128, n0 = blockIdx.y * 128;
    __shared__ unsigned short As[128 * 32];
    __shared__ unsigned short Bs[128 * 32];

    const int tid = threadIdx.x, lane = tid & 63, w = tid >> 6;
    const int quad = lane >> 4, r16 = lane & 15;
    const int mrow = (w >> 1) * 64, ncol = (w & 1) * 64;

    const f32x4 fz = {0.f, 0.f, 0.f, 0.f};
    f32x4 acc[4][4];
#pragma unroll
    for (int a = 0; a < 4; ++a)
#pragma unroll
        for (int b = 0; b < 4; ++b) acc[a][b] = fz;

    const int ci   = w << 1;
    const int rofs = lane >> 2, kofs = (lane & 3) * 8;
    const unsigned short* gA = X + (size_t)(m0 + ci * 16 + rofs) * 512 + kofs;
    const unsigned short* gB = Wt + (size_t)(n0 + ci * 16 + rofs) * 512 + kofs;
    unsigned short* lA = As + ci * 512 + lane * 8;
    unsigned short* lB = Bs + ci * 512 + lane * 8;

    for (int k0 = 0; k0 < 512; k0 += 32) {
        glds16(gA + k0, lA);
        glds16(gA + 16 * 512 + k0, lA + 512);
        glds16(gB + k0, lB);
        glds16(gB + 16 * 512 + k0, lB + 512);
        __syncthreads();

        bf16x8 af[4], bfr[4];
#pragma unroll
        for (int ms = 0; ms < 4; ++ms)
            af[ms] = *(const bf16x8*)(As + (mrow + ms * 16 + r16) * 32 + quad * 8);
#pragma unroll
        for (int ns = 0; ns < 4; ++ns)
            bfr[ns] = *(const bf16x8*)(Bs + (ncol + ns * 16 + r16) * 32 + quad * 8);
#pragma unroll
        for (int ms = 0; ms < 4; ++ms)
#pragma unroll
            for (int ns = 0; ns < 4; ++ns)
                acc[ms][ns] = __builtin_amdgcn_mfma_f32_16x16x32_bf16(
                    af[ms], bfr[ns], acc[ms][ns], 0, 0, 0);
        __syncthreads();
    }

#pragma unroll
    for (int ms = 0; ms < 4; ++ms)
#pragma unroll
        for (int ns = 0; ns < 4; ++ns) {
            int n = n0 + ncol + ns * 16 + r16;
            float bb = bias[n];
#pragma unroll
            for (int i = 0; i < 4; ++i) {
                int m = m0 + mrow + ms * 16 + quad * 4 + i;
                int bi = m >> 11, t = m & 2047;
                float v = acc[ms][ns][i] + bb;
                size_t idx = (t < 1024)
                    ? ((size_t)bi * 1024 + t) * 512 + n
                    : (size_t)2097152 + ((size_t)bi * 1024 + (t - 1024)) * 512 + n;
                out[idx] = v;
            }
        }
}

// ---------------------------------------------------------------------------
extern "C" void kernel_launch(void* const* d_in, const int* in_sizes, int n_in,
                              void* d_out, int out_size, void* d_ws, size_t ws_size,
                              hipStream_t stream)
{
    const float* self_seq  = (const float*)d_in[0];
    const float* cross_seq = (const float*)d_in[1];
    const int*   t_self    = (const int*)d_in[2];
    const int*   t_cross   = (const int*)d_in[3];
    const float* W_self    = (const float*)d_in[4];
    const float* b_self    = (const float*)d_in[5];
    const float* W_cross   = (const float*)d_in[6];
    const float* b_cross   = (const float*)d_in[7];
    const float* W_proj    = (const float*)d_in[8];
    const float* b_proj    = (const float*)d_in[9];
    float* out = (float*)d_out;

    // ws (32 MB): q, k, vt, y (4 x 4,194,304 bf16).
    // d_out (33.5 MB fp32) slack holds xb (8 MB) + wt (3 MB) + wtp (0.5 MB)
    // as scratch until proj overwrites everything.
    unsigned short* qbuf = (unsigned short*)d_ws;
    unsigned short* kbuf = qbuf + 4194304;
    unsigned short* vtb  = kbuf + 4194304;
    unsigned short* ybuf = vtb + 4194304;
    unsigned short* xb   = (unsigned short*)d_out;
    unsigned short* wt   = xb + 4194304;
    unsigned short* wtp  = wt + 1572864;

    prep_kernel<<<dim3(2496), 256, 0, stream>>>(
        self_seq, cross_seq, W_self, W_cross, W_proj, xb, wt, wtp);

    qkv_kernel<<<dim3(32, 12, 2), 256, 0, stream>>>(
        xb, wt, b_self, b_cross, qbuf, kbuf, vtb);

    attn_kernel<<<dim3(1024), 256, 0, stream>>>(
        qbuf, kbuf, vtb, t_self, t_cross, ybuf);

    proj_kernel<<<dim3(64, 4), 256, 0, stream>>>(
        ybuf, W_proj != nullptr ? wtp : wtp, b_proj, out);
}